// Round 2
// baseline (154.435 us; speedup 1.0000x reference)
//
#include <hip/hip_runtime.h>

#define XD 192
#define YD 192
#define CCH 3
#define IMG 224

#define NCONV 576          // 12 x-tiles * 3 channels * 16 q-phases
#define QSPLIT 16
#define NAFF 9216          // 36864 pixels / 4 waves per block

// Fused kernel:
//  blocks [0, NCONV): lateral convolutions (inh 94x94 + exc 38x38), LDS-staged
//  blocks [NCONV, NCONV+NAFF): afferent dot products, 1 wave per output pixel
// Everything atomicAdds into out (zeroed by memset before launch) -> no
// inter-kernel dependency, conv VALU work hides under afferent HBM stream.
__global__ __launch_bounds__(256, 4) void k_fused(
    const float* __restrict__ input, const float* __restrict__ affw,
    const float* __restrict__ affm, const float* __restrict__ exw,
    const float* __restrict__ exm,  const float* __restrict__ inw,
    const float* __restrict__ inm,  const float* __restrict__ oldact,
    const int*   __restrict__ rfstart, float* __restrict__ out)
{
    __shared__ float s_act[16][288];
    __shared__ float s_k[96];

    const int bid = blockIdx.x;
    const int tid = threadIdx.x;

    if (bid < NCONV) {
        // ---------------- lateral conv ----------------
        const int xt = bid % 12;
        const int c  = (bid / 12) % 3;
        const int q  = bid / 36;            // 0..15
        const int x0 = xt * 16;
        const int yg = tid & 15;            // 16 y-groups
        const int xr = tid >> 4;            // 16 x-rows
        const int y0 = yg * 12;             // 12 outputs per thread

        float acc[12];
        #pragma unroll
        for (int t = 0; t < 12; ++t) acc[t] = 0.f;

        // ---- inhibitory 94x94, weights pre-scaled by -0.9 ----
        // staged act: s_act[row][t] = old[c][r0+row][t-47], t in [0,288)
        for (int i = q; i < 94; i += QSPLIT) {
            const int r0 = x0 + i - 47;
            if (r0 + 15 < 0 || r0 > 191) continue;   // block-uniform
            __syncthreads();
            if (tid < 96)
                s_k[tid] = (tid < 94) ? (-0.9f * inw[i * 94 + tid] * inm[i * 94 + tid]) : 0.f;
            {
                const int row = tid & 15;
                const int cb  = (tid >> 4) * 18;     // 288/16 = 18 cols/thread
                const int rr  = r0 + row;
                const bool rok = (rr >= 0 && rr < XD);
                const float* src = oldact + ((size_t)c * XD + rr) * YD;
                #pragma unroll
                for (int k = 0; k < 18; ++k) {
                    const int t = cb + k;
                    const int col = t - 47;
                    s_act[row][t] = (rok && col >= 0 && col < YD) ? src[col] : 0.f;
                }
            }
            __syncthreads();

            const float* arow = s_act[xr];
            float w[16];
            #pragma unroll
            for (int k = 0; k < 4; ++k) {
                const float4 t4 = *(const float4*)(arow + y0 + 4 * k);
                w[4*k+0] = t4.x; w[4*k+1] = t4.y; w[4*k+2] = t4.z; w[4*k+3] = t4.w;
            }
            #pragma unroll
            for (int g = 0; g < 24; ++g) {
                const float4 k4 = *(const float4*)(s_k + 4 * g);
                #pragma unroll
                for (int t = 0; t < 12; ++t) {
                    acc[t] += k4.x * w[t + 0];
                    acc[t] += k4.y * w[t + 1];
                    acc[t] += k4.z * w[t + 2];
                    acc[t] += k4.w * w[t + 3];
                }
                if (g < 23) {
                    #pragma unroll
                    for (int k = 0; k < 12; ++k) w[k] = w[k + 4];
                    const float4 n4 = *(const float4*)(arow + y0 + 4 * g + 16);
                    w[12] = n4.x; w[13] = n4.y; w[14] = n4.z; w[15] = n4.w;
                }
            }
        }

        // ---- excitatory 38x38, weights pre-scaled by +0.9 ----
        // staged act: s_act[row][t] = old[c][r0+row][t-19], t in [0,240)
        for (int i = q; i < 38; i += QSPLIT) {
            const int r0 = x0 + i - 19;
            if (r0 + 15 < 0 || r0 > 191) continue;
            __syncthreads();
            if (tid < 40)
                s_k[tid] = (tid < 38) ? (0.9f * exw[i * 38 + tid] * exm[i * 38 + tid]) : 0.f;
            {
                const int row = tid & 15;
                const int cb  = (tid >> 4) * 15;     // 240/16 = 15 cols/thread
                const int rr  = r0 + row;
                const bool rok = (rr >= 0 && rr < XD);
                const float* src = oldact + ((size_t)c * XD + rr) * YD;
                #pragma unroll
                for (int k = 0; k < 15; ++k) {
                    const int t = cb + k;
                    const int col = t - 19;
                    s_act[row][t] = (rok && col >= 0 && col < YD) ? src[col] : 0.f;
                }
            }
            __syncthreads();

            const float* arow = s_act[xr];
            float w[16];
            #pragma unroll
            for (int k = 0; k < 4; ++k) {
                const float4 t4 = *(const float4*)(arow + y0 + 4 * k);
                w[4*k+0] = t4.x; w[4*k+1] = t4.y; w[4*k+2] = t4.z; w[4*k+3] = t4.w;
            }
            #pragma unroll
            for (int g = 0; g < 10; ++g) {
                const float4 k4 = *(const float4*)(s_k + 4 * g);
                #pragma unroll
                for (int t = 0; t < 12; ++t) {
                    acc[t] += k4.x * w[t + 0];
                    acc[t] += k4.y * w[t + 1];
                    acc[t] += k4.z * w[t + 2];
                    acc[t] += k4.w * w[t + 3];
                }
                if (g < 9) {
                    #pragma unroll
                    for (int k = 0; k < 12; ++k) w[k] = w[k + 4];
                    const float4 n4 = *(const float4*)(arow + y0 + 4 * g + 16);
                    w[12] = n4.x; w[13] = n4.y; w[14] = n4.z; w[15] = n4.w;
                }
            }
        }

        float* op = out + ((size_t)c * XD + (x0 + xr)) * YD + y0;
        #pragma unroll
        for (int t = 0; t < 12; ++t) atomicAdd(&op[t], acc[t]);

    } else {
        // ---------------- afferent ----------------
        const int xy   = (bid - NCONV) * 4 + (tid >> 6);
        const int lane = tid & 63;
        const int sx = rfstart[xy * 2 + 0];
        const int sy = rfstart[xy * 2 + 1];
        const float4* W4 = (const float4*)affw + (size_t)xy * 144;
        const float4* M4 = (const float4*)affm;
        float acc = 0.f;
        #pragma unroll
        for (int it = 0; it < 7; ++it) {
            const int g = lane + (it << 6);            // 432 = 6*64 + 48
            if (it < 6 || lane < 48) {
                const int c = (g >= 288) ? 2 : ((g >= 144) ? 1 : 0);
                const int r = g - c * 144;
                const float4 w4 = W4[(size_t)c * 5308416 + r];   // 36864*144
                const float4 m4 = M4[r];
                const int u = (r * 2731) >> 14;        // r/6
                const int v = (r - u * 6) << 2;
                const float* ip = input + c * (IMG * IMG) + (sx + u) * IMG + (sy + v);
                acc += ip[0] * m4.x * w4.x;
                acc += ip[1] * m4.y * w4.y;
                acc += ip[2] * m4.z * w4.z;
                acc += ip[3] * m4.w * w4.w;
            }
        }
        #pragma unroll
        for (int off = 32; off > 0; off >>= 1) acc += __shfl_xor(acc, off);
        if (lane < 3) atomicAdd(out + (size_t)lane * (XD * YD) + xy, acc);
    }
}

extern "C" void kernel_launch(void* const* d_in, const int* in_sizes, int n_in,
                              void* d_out, int out_size, void* d_ws, size_t ws_size,
                              hipStream_t stream)
{
    const float* input   = (const float*)d_in[0];
    const float* affw    = (const float*)d_in[1];
    const float* exw     = (const float*)d_in[2];
    const float* inw     = (const float*)d_in[3];
    const float* affm    = (const float*)d_in[4];
    const float* exm     = (const float*)d_in[5];
    const float* inm     = (const float*)d_in[6];
    const float* oldact  = (const float*)d_in[7];
    const int*   rfstart = (const int*)d_in[8];
    float* out = (float*)d_out;

    hipMemsetAsync(d_out, 0, sizeof(float) * CCH * XD * YD, stream);

    hipLaunchKernelGGL(k_fused, dim3(NCONV + NAFF), dim3(256), 0, stream,
                       input, affw, affm, exw, exm, inw, inm, oldact, rfstart, out);
}

// Round 3
// 95.991 us; speedup vs baseline: 1.6089x; 1.6089x over previous
//
#include <hip/hip_runtime.h>

#define XD 192
#define YD 192
#define CCH 3
#define IMG 224

// ---- ws layout (float offsets) ----
#define OFF_PAD 0
#define PADW 320                        // act row padded: col = y + 64
#define N_PAD (CCH*XD*PADW)             // 184320
#define OFF_KI (OFF_PAD + N_PAD)
#define KI_LD 96                        // 94 cols + 2 zero pad
#define N_KI (94*KI_LD)
#define OFF_KE (OFF_KI + N_KI)
#define KE_LD 40                        // 38 cols + 2 zero pad
#define N_KE (38*KE_LD)

#define N_OUT (CCH*XD*YD)               // 110592

#define QSPLIT 8
#define NCONV 576                       // 24 x-tiles * 3 ch * 8 q-phases
#define NAFF 9216                       // 36864 pixels / 4 waves per block

// Prep: zero the output, build padded activation rows and masked,
// gamma-prescaled lateral kernels in ws. ~1.2 MB of writes, ~4 us.
__global__ __launch_bounds__(256) void k_prep(
    const float* __restrict__ exw, const float* __restrict__ exm,
    const float* __restrict__ inw, const float* __restrict__ inm,
    const float* __restrict__ oldact, float* __restrict__ ws,
    float* __restrict__ out)
{
    const int TOT = N_OUT + N_PAD + N_KI + N_KE;
    for (int idx = blockIdx.x * 256 + threadIdx.x; idx < TOT; idx += gridDim.x * 256) {
        if (idx < N_OUT) {
            out[idx] = 0.f;
        } else if (idx < N_OUT + N_PAD) {
            const int k = idx - N_OUT;
            const int col = k % PADW;
            const int rem = k / PADW;
            float v = 0.f;
            if (col >= 64 && col < 64 + YD)
                v = oldact[rem * YD + (col - 64)];
            ws[OFF_PAD + k] = v;
        } else if (idx < N_OUT + N_PAD + N_KI) {
            const int k = idx - N_OUT - N_PAD;
            const int i = k / KI_LD, j = k % KI_LD;
            ws[OFF_KI + k] = (j < 94) ? (-0.9f * inw[i * 94 + j] * inm[i * 94 + j]) : 0.f;
        } else {
            const int k = idx - N_OUT - N_PAD - N_KI;
            const int i = k / KE_LD, j = k % KE_LD;
            ws[OFF_KE + k] = (j < 38) ? (0.9f * exw[i * 38 + j] * exm[i * 38 + j]) : 0.f;
        }
    }
}

// Fused kernel:
//  blocks [0, NCONV): lateral conv, register sliding window, reads padded
//    rows from ws (L1/L2-cached, no LDS -> no bank conflicts, no syncs)
//  blocks [NCONV, ...): afferent dot products, 1 wave per output pixel,
//    input gather via single unaligned float4 loads (4x fewer TA ops)
// Both atomicAdd into out (zeroed by k_prep).
__global__ __launch_bounds__(256) void k_fused(
    const float* __restrict__ input, const float* __restrict__ affw,
    const float* __restrict__ affm, const int* __restrict__ rfstart,
    const float* __restrict__ ws, float* __restrict__ out)
{
    const int bid = blockIdx.x;
    const int tid = threadIdx.x;

    if (bid < NCONV) {
        // ---------------- lateral conv ----------------
        const int xt = bid % 24;
        const int c  = (bid / 24) % 3;
        const int q  = bid / 72;            // 0..7
        const int yg = tid & 31;
        const int xr = tid >> 5;
        const int x  = xt * 8 + xr;
        const int y0 = yg * 6;

        float acc[6] = {0.f, 0.f, 0.f, 0.f, 0.f, 0.f};
        const float* pad = ws + OFF_PAD + (size_t)c * XD * PADW;

        // inhibitory 94x94 (pre-scaled by -0.9), pad col = y + j + 17
        for (int i = q; i < 94; i += QSPLIT) {
            const int r = x + i - 47;
            if (r < 0 || r >= XD) continue;
            const float* row = pad + r * PADW + y0 + 17;
            const float4* kw = (const float4*)(ws + OFF_KI + i * KI_LD);
            float w[9];
            #pragma unroll
            for (int k = 0; k < 9; ++k) w[k] = row[k];
            #pragma unroll
            for (int g = 0; g < 24; ++g) {
                const float4 k4 = kw[g];
                #pragma unroll
                for (int t = 0; t < 6; ++t) {
                    acc[t] += k4.x * w[0 + t];
                    acc[t] += k4.y * w[1 + t];
                    acc[t] += k4.z * w[2 + t];
                    acc[t] += k4.w * w[3 + t];
                }
                #pragma unroll
                for (int k = 0; k < 5; ++k) w[k] = w[k + 4];
                #pragma unroll
                for (int k = 5; k < 9; ++k) w[k] = row[4 * (g + 1) + k];
            }
        }

        // excitatory 38x38 (pre-scaled by +0.9), pad col = y + j + 45
        for (int i = q; i < 38; i += QSPLIT) {
            const int r = x + i - 19;
            if (r < 0 || r >= XD) continue;
            const float* row = pad + r * PADW + y0 + 45;
            const float4* kw = (const float4*)(ws + OFF_KE + i * KE_LD);
            float w[9];
            #pragma unroll
            for (int k = 0; k < 9; ++k) w[k] = row[k];
            #pragma unroll
            for (int g = 0; g < 10; ++g) {
                const float4 k4 = kw[g];
                #pragma unroll
                for (int t = 0; t < 6; ++t) {
                    acc[t] += k4.x * w[0 + t];
                    acc[t] += k4.y * w[1 + t];
                    acc[t] += k4.z * w[2 + t];
                    acc[t] += k4.w * w[3 + t];
                }
                #pragma unroll
                for (int k = 0; k < 5; ++k) w[k] = w[k + 4];
                #pragma unroll
                for (int k = 5; k < 9; ++k) w[k] = row[4 * (g + 1) + k];
            }
        }

        float* op = out + ((size_t)c * XD + x) * YD + y0;
        #pragma unroll
        for (int t = 0; t < 6; ++t) atomicAdd(&op[t], acc[t]);

    } else {
        // ---------------- afferent ----------------
        const int xy   = (bid - NCONV) * 4 + (tid >> 6);
        const int lane = tid & 63;
        const int sx = rfstart[xy * 2 + 0];
        const int sy = rfstart[xy * 2 + 1];
        const float4* W4 = (const float4*)affw + (size_t)xy * 144;
        const float4* M4 = (const float4*)affm;
        float acc = 0.f;
        #pragma unroll
        for (int it = 0; it < 7; ++it) {
            const int g = lane + (it << 6);            // 432 = 6*64 + 48
            if (it < 6 || lane < 48) {
                const int c = (g >= 288) ? 2 : ((g >= 144) ? 1 : 0);
                const int r = g - c * 144;
                const float4 w4 = W4[(size_t)c * 5308416 + r];   // 36864*144
                const float4 m4 = M4[r];
                const int u = (r * 2731) >> 14;        // r/6
                const int v = (r - u * 6) << 2;
                const float* ip = input + c * (IMG * IMG) + (sx + u) * IMG + (sy + v);
                float4 iv;                              // unaligned 16B load
                __builtin_memcpy(&iv, ip, sizeof(float4));
                acc += iv.x * m4.x * w4.x;
                acc += iv.y * m4.y * w4.y;
                acc += iv.z * m4.z * w4.z;
                acc += iv.w * m4.w * w4.w;
            }
        }
        #pragma unroll
        for (int off = 32; off > 0; off >>= 1) acc += __shfl_xor(acc, off);
        if (lane < 3) atomicAdd(out + (size_t)lane * (XD * YD) + xy, acc);
    }
}

extern "C" void kernel_launch(void* const* d_in, const int* in_sizes, int n_in,
                              void* d_out, int out_size, void* d_ws, size_t ws_size,
                              hipStream_t stream)
{
    const float* input   = (const float*)d_in[0];
    const float* affw    = (const float*)d_in[1];
    const float* exw     = (const float*)d_in[2];
    const float* inw     = (const float*)d_in[3];
    const float* affm    = (const float*)d_in[4];
    const float* exm     = (const float*)d_in[5];
    const float* inm     = (const float*)d_in[6];
    const float* oldact  = (const float*)d_in[7];
    const int*   rfstart = (const int*)d_in[8];
    float* out = (float*)d_out;
    float* ws  = (float*)d_ws;

    hipLaunchKernelGGL(k_prep, dim3(1194), dim3(256), 0, stream,
                       exw, exm, inw, inm, oldact, ws, out);

    hipLaunchKernelGGL(k_fused, dim3(NCONV + NAFF), dim3(256), 0, stream,
                       input, affw, affm, rfstart, ws, out);
}